// Round 2
// baseline (5084.125 us; speedup 1.0000x reference)
//
#include <hip/hip_runtime.h>

// ---- constants ----
#define BB 4
#define TT 1024
#define CC 1024
#define NH 16
#define NKV 4
#define HD 64
#define FFNH 4096
#define CAD 32

__device__ __forceinline__ float sigf(float x){ return 1.f/(1.f+__expf(-x)); }
__device__ __forceinline__ float geluf(float x){ return 0.5f*x*(1.f+erff(x*0.70710678118654752f)); }

// ---- rmsnorm over last dim (1024) ----
__global__ __launch_bounds__(256) void rmsnorm_k(const float* __restrict__ x, float* __restrict__ o){
  int row = blockIdx.x;
  const float* xr = x + (size_t)row * CC;
  float v[4]; float ss = 0.f;
  #pragma unroll
  for (int i = 0; i < 4; i++){ v[i] = xr[threadIdx.x + 256*i]; ss += v[i]*v[i]; }
  #pragma unroll
  for (int off = 1; off < 64; off <<= 1) ss += __shfl_xor(ss, off);
  __shared__ float red[4];
  if ((threadIdx.x & 63) == 0) red[threadIdx.x >> 6] = ss;
  __syncthreads();
  float tot = red[0]+red[1]+red[2]+red[3];
  float rs = rsqrtf(tot * (1.f/CC) + 1e-6f);
  float* orow = o + (size_t)row * CC;
  #pragma unroll
  for (int i = 0; i < 4; i++) orow[threadIdx.x + 256*i] = v[i]*rs;
}

// ---- generic GEMM: C[M,N] = A[M,K] * W[N,K]^T (all fp32), EPI 0=none 1=relu^2 ----
template<int EPI>
__global__ __launch_bounds__(256) void gemm_k(
    const float* __restrict__ A, const float* __restrict__ W,
    float* __restrict__ C, int M, int N, int K)
{
  __shared__ float As[16][68];
  __shared__ float Ws[16][68];
  int tid = threadIdx.x;
  int m0 = blockIdx.y << 6;
  int n0 = blockIdx.x << 6;
  int lm = tid >> 2;
  int lk = (tid & 3) << 2;
  int tx = tid & 15;
  int ty = tid >> 4;
  float acc[4][4] = {};
  const float* Ap = A + (size_t)(m0 + lm)*K + lk;
  const float* Wp = W + (size_t)(n0 + lm)*K + lk;
  for (int k0 = 0; k0 < K; k0 += 16){
    float4 a4 = *(const float4*)(Ap + k0);
    float4 w4 = *(const float4*)(Wp + k0);
    As[lk+0][lm]=a4.x; As[lk+1][lm]=a4.y; As[lk+2][lm]=a4.z; As[lk+3][lm]=a4.w;
    Ws[lk+0][lm]=w4.x; Ws[lk+1][lm]=w4.y; Ws[lk+2][lm]=w4.z; Ws[lk+3][lm]=w4.w;
    __syncthreads();
    #pragma unroll
    for (int kk = 0; kk < 16; kk++){
      float a[4], bb[4];
      #pragma unroll
      for (int i=0;i<4;i++) a[i] = As[kk][ty*4+i];
      #pragma unroll
      for (int j=0;j<4;j++) bb[j] = Ws[kk][tx*4+j];
      #pragma unroll
      for (int i=0;i<4;i++)
        #pragma unroll
        for (int j=0;j<4;j++) acc[i][j] += a[i]*bb[j];
    }
    __syncthreads();
  }
  #pragma unroll
  for (int i=0;i<4;i++){
    float* cp = C + (size_t)(m0 + ty*4 + i)*N + n0 + tx*4;
    float4 o;
    float z;
    z = acc[i][0]; if (EPI==1){ z = fmaxf(z,0.f); z = z*z; } o.x = z;
    z = acc[i][1]; if (EPI==1){ z = fmaxf(z,0.f); z = z*z; } o.y = z;
    z = acc[i][2]; if (EPI==1){ z = fmaxf(z,0.f); z = z*z; } o.z = z;
    z = acc[i][3]; if (EPI==1){ z = fmaxf(z,0.f); z = z*z; } o.w = z;
    *(float4*)cp = o;
  }
}

// ---- rope + head-rmsnorm * 1.2 (one wave per (b,t,head)) ----
__global__ __launch_bounds__(64) void rope_rms_k(float* __restrict__ q,
    const float* __restrict__ cs, const float* __restrict__ sn, int nh){
  int idx = blockIdx.x;                 // (b*T + t)*nh + h
  int t = (idx / nh) & (TT-1);
  float* qp = q + (size_t)idx * HD;
  int d = threadIdx.x;
  int dl = d & 31;
  float c = cs[t*32 + dl], s = sn[t*32 + dl];
  float v0 = qp[d];
  float vp = qp[(d < 32) ? d + 32 : d - 32];
  float r = (d < 32) ? (v0*c + vp*s) : (v0*c - vp*s);
  float ss = r*r;
  #pragma unroll
  for (int off = 1; off < 64; off <<= 1) ss += __shfl_xor(ss, off);
  float rs = rsqrtf(ss*(1.f/HD) + 1e-6f) * 1.2f;
  qp[d] = r*rs;
}

// ---- v += 3*sigmoid(xn[:,:12] @ wg^T) * ve ----
__global__ __launch_bounds__(256) void gatev_k(float* __restrict__ v,
    const float* __restrict__ xn, const float* __restrict__ ve,
    const float* __restrict__ wg){
  int bt = blockIdx.x;
  int tid = threadIdx.x;
  int kv = tid >> 6;
  float s = 0.f;
  #pragma unroll
  for (int j = 0; j < 12; j++) s += xn[(size_t)bt*CC + j]*wg[kv*12+j];
  float gate = 3.f * sigf(s);
  size_t i = (size_t)bt*(NKV*HD) + tid;
  v[i] += gate * ve[i];
}

// ---- attention: one block per (b,h,t); scores row in LDS; refine conv fused ----
__global__ __launch_bounds__(256) void attn_k(
    const float* __restrict__ q, const float* __restrict__ k, const float* __restrict__ v,
    const float* __restrict__ pa, const float* __restrict__ rw,
    const float* __restrict__ alphap, float* __restrict__ y)
{
  int idx = blockIdx.x;
  int t  = idx & (TT-1);
  int bh = idx >> 10;
  int h  = bh & (NH-1);
  int b  = bh >> 4;
  int kv = h >> 2;
  int tid = threadIdx.x;
  __shared__ float sc[TT];
  __shared__ float qs[HD];
  __shared__ float red[4];
  __shared__ float yred[4][HD];
  if (tid < HD) qs[tid] = q[(((size_t)(b*TT + t))*NH + h)*HD + tid];
  float alpha = *alphap;
  float w9[9];
  #pragma unroll
  for (int j = 0; j < 9; j++) w9[j] = rw[h*9+j] * alpha;
  __syncthreads();
  int nk = t + 1;
  const float* kbp = k + ((size_t)b*TT*NKV + kv)*HD;
  const float* pab = pa + ((size_t)(b*NH + h))*TT*TT;
  float lmax = -1e30f;
  for (int kk = tid; kk < nk; kk += 256){
    const float* kp = kbp + (size_t)kk*(NKV*HD);
    float s = 0.f;
    #pragma unroll
    for (int d2 = 0; d2 < HD; d2++) s += qs[d2]*kp[d2];
    s *= 0.125f;
    float cv = 0.f;
    #pragma unroll
    for (int dy = 0; dy < 3; dy++){
      int ti = t + dy - 1;
      if (ti < 0 || ti >= TT) continue;
      const float* pr = pab + (size_t)ti*TT;
      #pragma unroll
      for (int dx = 0; dx < 3; dx++){
        int kj = kk + dx - 1;
        if (kj < 0 || kj >= TT) continue;
        cv += pr[kj] * w9[dy*3+dx];
      }
    }
    s += cv;
    sc[kk] = s;
    lmax = fmaxf(lmax, s);
  }
  #pragma unroll
  for (int off = 1; off < 64; off <<= 1) lmax = fmaxf(lmax, __shfl_xor(lmax, off));
  if ((tid & 63) == 0) red[tid >> 6] = lmax;
  __syncthreads();
  float M = fmaxf(fmaxf(red[0],red[1]),fmaxf(red[2],red[3]));
  __syncthreads();
  float lsum = 0.f;
  for (int kk = tid; kk < nk; kk += 256){
    float p = __expf(sc[kk]-M);
    sc[kk] = p;
    lsum += p;
  }
  #pragma unroll
  for (int off = 1; off < 64; off <<= 1) lsum += __shfl_xor(lsum, off);
  if ((tid & 63) == 0) red[tid >> 6] = lsum;
  __syncthreads();
  float inv = 1.f / (red[0]+red[1]+red[2]+red[3]);
  int d  = tid & 63;
  int sl = tid >> 6;
  const float* vbp = v + ((size_t)b*TT*NKV + kv)*HD + d;
  float acc = 0.f;
  for (int kk = sl; kk < nk; kk += 4) acc += sc[kk] * vbp[(size_t)kk*(NKV*HD)];
  yred[sl][d] = acc;
  __syncthreads();
  if (tid < HD)
    y[(((size_t)(b*TT + t))*NH + h)*HD + tid] =
      (yred[0][tid]+yred[1][tid]+yred[2][tid]+yred[3][tid]) * inv;
}

// ---- CA: in-projection (K=1024 -> 32) ----
__global__ __launch_bounds__(256) void cain_k(const float* __restrict__ x,
    const float* __restrict__ pi, float* __restrict__ out){
  int bt = blockIdx.x;
  __shared__ float xs[CC];
  __shared__ float pr[8][33];
  for (int i = threadIdx.x; i < CC; i += 256) xs[i] = x[(size_t)bt*CC + i];
  __syncthreads();
  int d = threadIdx.x & 31, sl = threadIdx.x >> 5;
  const float* pip = pi + (size_t)d*CC + sl*128;
  float s = 0.f;
  #pragma unroll 8
  for (int i = 0; i < 128; i++) s += xs[sl*128+i]*pip[i];
  pr[sl][d] = s;
  __syncthreads();
  if (threadIdx.x < 32){
    float tot = 0.f;
    #pragma unroll
    for (int j = 0; j < 8; j++) tot += pr[j][threadIdx.x];
    out[(size_t)bt*CAD + threadIdx.x] = tot;
  }
}

// ---- CA: depthwise conv over T + exact gelu ----
__global__ __launch_bounds__(256) void caconv_k(const float* __restrict__ hin,
    const float* __restrict__ cw, float* __restrict__ gout){
  int i = blockIdx.x*256 + threadIdx.x;   // < B*T*32
  int d = i & 31;
  int bt = i >> 5;
  int t = bt & (TT-1);
  float cc = hin[i];
  float hm = (t > 0)      ? hin[i-32] : 0.f;
  float hp = (t < TT-1)   ? hin[i+32] : 0.f;
  float hc = cc + 0.1f*(hm*cw[d*3] + cc*cw[d*3+1] + hp*cw[d*3+2]);
  gout[i] = geluf(hc);
}

// ---- CA: out-projection (K=32 -> 1024) ----
__global__ __launch_bounds__(256) void caout_k(const float* __restrict__ g,
    const float* __restrict__ po, float* __restrict__ out){
  int bt = blockIdx.x;
  __shared__ float gs[CAD];
  if (threadIdx.x < CAD) gs[threadIdx.x] = g[(size_t)bt*CAD + threadIdx.x];
  __syncthreads();
  for (int c = threadIdx.x; c < CC; c += 256){
    const float* pp = po + (size_t)c*CAD;
    float s = 0.f;
    #pragma unroll
    for (int d2 = 0; d2 < CAD; d2++) s += gs[d2]*pp[d2];
    out[(size_t)bt*CC + c] = s;
  }
}

// ---- x1 = x + attn_out * (1 + 0.1*tanh(ca1)) ----
__global__ __launch_bounds__(256) void x1_k(const float* __restrict__ x,
    const float* __restrict__ ao, const float* __restrict__ ca1, float* __restrict__ x1){
  size_t i = (size_t)blockIdx.x*256 + threadIdx.x;
  x1[i] = x[i] + ao[i] * (1.f + 0.1f*tanhf(ca1[i]));
}

// ---- FFN depthwise conv over T (one of 4 iterations) ----
__global__ __launch_bounds__(256) void ffnconv_k(const float* __restrict__ hin,
    const float* __restrict__ cw, float* __restrict__ hout){
  size_t i = (size_t)blockIdx.x*256 + threadIdx.x;   // < B*T*4096
  int c = (int)(i & (FFNH-1));
  size_t bt = i >> 12;
  int t = (int)(bt & (TT-1));
  float cc = hin[i];
  float hm = (t > 0)    ? hin[i - FFNH] : 0.f;
  float hp = (t < TT-1) ? hin[i + FFNH] : 0.f;
  hout[i] = cc + 0.1f*(hm*cw[c*3] + cc*cw[c*3+1] + hp*cw[c*3+2]);
}

// ---- vit scalar gate ----
__global__ __launch_bounds__(256) void vit_k(const float* __restrict__ x1,
    const float* __restrict__ w1, const float* __restrict__ w2,
    float* __restrict__ vout){
  int bt = blockIdx.x;
  __shared__ float xs[CC];
  __shared__ float pr[8][33];
  __shared__ float g32[32];
  for (int i = threadIdx.x; i < CC; i += 256) xs[i] = x1[(size_t)bt*CC + i];
  __syncthreads();
  int d = threadIdx.x & 31, sl = threadIdx.x >> 5;
  const float* wp = w1 + (size_t)d*CC + sl*128;
  float s = 0.f;
  #pragma unroll 8
  for (int i = 0; i < 128; i++) s += xs[sl*128+i]*wp[i];
  pr[sl][d] = s;
  __syncthreads();
  if (threadIdx.x < 32){
    float tot = 0.f;
    #pragma unroll
    for (int j = 0; j < 8; j++) tot += pr[j][threadIdx.x];
    g32[threadIdx.x] = geluf(tot);
  }
  __syncthreads();
  if (threadIdx.x == 0){
    float s2 = 0.f;
    #pragma unroll
    for (int d2 = 0; d2 < 32; d2++) s2 += g32[d2]*w2[d2];
    vout[bt] = sigf(s2);
  }
}

// ---- vit smoothing + threshold ----
__global__ __launch_bounds__(256) void vitsm_k(const float* __restrict__ vin, float* __restrict__ vout){
  int i = blockIdx.x*256 + threadIdx.x;  // < B*T
  int t = i & (TT-1), b = i >> 10;
  float s = 0.f;
  #pragma unroll
  for (int dd = -2; dd <= 2; dd++){
    int tt = t + dd;
    if (tt >= 0 && tt < TT) s += vin[(b << 10) + tt];
  }
  s *= 0.2f;
  float vv = 0.7f*vin[i] + 0.3f*s;
  vout[i] = (vv > 0.3f) ? vv : 0.1f*vv;
}

// ---- final: out = x1 + mlp*sig(g)*(1+0.1*tanh(ca2)) * vit ----
__global__ __launch_bounds__(256) void final_k(const float* __restrict__ x1,
    const float* __restrict__ mlpraw, const float* __restrict__ g,
    const float* __restrict__ ca2, const float* __restrict__ vsm,
    float* __restrict__ out){
  size_t i = (size_t)blockIdx.x*256 + threadIdx.x;
  size_t bt = i >> 10;
  float mlp = mlpraw[i] * sigf(g[i]) * (1.f + 0.1f*tanhf(ca2[i]));
  out[i] = x1[i] + mlp * vsm[bt];
}

extern "C" void kernel_launch(void* const* d_in, const int* in_sizes, int n_in,
                              void* d_out, int out_size, void* d_ws, size_t ws_size,
                              hipStream_t stream) {
  (void)in_sizes; (void)n_in; (void)out_size; (void)ws_size;
  const float* x     = (const float*)d_in[0];
  const float* ve    = (const float*)d_in[1];
  const float* cs    = (const float*)d_in[2];
  const float* sn    = (const float*)d_in[3];
  const float* pa    = (const float*)d_in[4];
  const float* w_q   = (const float*)d_in[5];
  const float* w_k   = (const float*)d_in[6];
  const float* w_v   = (const float*)d_in[7];
  const float* w_o   = (const float*)d_in[8];
  const float* w_vg  = (const float*)d_in[9];
  const float* rfw   = (const float*)d_in[10];
  const float* ralp  = (const float*)d_in[11];
  const float* capi  = (const float*)d_in[12];
  const float* cacw  = (const float*)d_in[13];
  const float* capo  = (const float*)d_in[14];
  const float* ffin  = (const float*)d_in[15];
  const float* ffcw  = (const float*)d_in[16];
  const float* ffout = (const float*)d_in[17];
  const float* ffgt  = (const float*)d_in[18];
  const float* vw1   = (const float*)d_in[19];
  const float* vw2   = (const float*)d_in[20];

  float* ws = (float*)d_ws;
  const size_t M4 = (size_t)BB*TT*CC;       // 4,194,304
  float* xn  = ws;                          // M4   (reused: ca1)
  float* qb  = ws + M4;                     // M4   (reused: ffn gate)
  float* kb  = ws + 2*M4;                   // M4/4
  float* vb  = ws + 2*M4 + M4/4;            // M4/4
  float* yb  = ws + 2*M4 + M4/2;            // M4   (reused: ca2)
  float* ao  = ws + 3*M4 + M4/2;            // M4   (reused: mlp raw)
  float* x1b = ws + 4*M4 + M4/2;            // M4
  float* xm  = ws + 5*M4 + M4/2;            // M4
  float* hb  = ws + 6*M4 + M4/2;            // 4*M4
  float* h2  = ws + 10*M4 + M4/2;           // 4*M4
  float* cah = ws + 14*M4 + M4/2;           // 128K
  float* cag = cah + (size_t)BB*TT*CAD;     // 128K
  float* vtb = cag + (size_t)BB*TT*CAD;     // 4K
  float* vsm = vtb + (size_t)BB*TT;         // 4K

  const int BT = BB*TT;                     // 4096

  // xn = rmsnorm(x)
  rmsnorm_k<<<BT, 256, 0, stream>>>(x, xn);
  // q,k,v projections
  gemm_k<0><<<dim3(16, 64), 256, 0, stream>>>(xn, w_q, qb, BT, 1024, 1024);
  gemm_k<0><<<dim3(4, 64), 256, 0, stream>>>(xn, w_k, kb, BT, 256, 1024);
  gemm_k<0><<<dim3(4, 64), 256, 0, stream>>>(xn, w_v, vb, BT, 256, 1024);
  // rope + head rmsnorm
  rope_rms_k<<<BT*NH, 64, 0, stream>>>(qb, cs, sn, NH);
  rope_rms_k<<<BT*NKV, 64, 0, stream>>>(kb, cs, sn, NKV);
  // value-embedding gate
  gatev_k<<<BT, 256, 0, stream>>>(vb, xn, ve, w_vg);
  // attention with fused refine conv + causal softmax
  attn_k<<<BB*NH*TT, 256, 0, stream>>>(qb, kb, vb, pa, rfw, ralp, yb);
  // output projection
  gemm_k<0><<<dim3(16, 64), 256, 0, stream>>>(yb, w_o, ao, BT, 1024, 1024);
  // ca1 = ca_channel(x)  -> into xn (free after gatev)
  cain_k<<<BT, 256, 0, stream>>>(x, capi, cah);
  caconv_k<<<BT*CAD/256, 256, 0, stream>>>(cah, cacw, cag);
  caout_k<<<BT, 256, 0, stream>>>(cag, capo, xn);
  // x1 = x + ao*(1+0.1*tanh(ca1))
  x1_k<<<BT*CC/256, 256, 0, stream>>>(x, ao, xn, x1b);
  // xm = rmsnorm(x1)
  rmsnorm_k<<<BT, 256, 0, stream>>>(x1b, xm);
  // h = relu(xm @ ffn_in^T)^2
  gemm_k<1><<<dim3(64, 64), 256, 0, stream>>>(xm, ffin, hb, BT, FFNH, 1024);
  // 4x: h = h + 0.1*dwconv(h)
  ffnconv_k<<<BT*FFNH/256, 256, 0, stream>>>(hb, ffcw, h2);
  ffnconv_k<<<BT*FFNH/256, 256, 0, stream>>>(h2, ffcw, hb);
  ffnconv_k<<<BT*FFNH/256, 256, 0, stream>>>(hb, ffcw, h2);
  ffnconv_k<<<BT*FFNH/256, 256, 0, stream>>>(h2, ffcw, hb);
  // gate = xm @ ffn_gate^T  -> qb (free after attn)
  gemm_k<0><<<dim3(16, 64), 256, 0, stream>>>(xm, ffgt, qb, BT, 1024, 1024);
  // mlp_raw = h @ ffn_out^T -> ao (free after x1_k)
  gemm_k<0><<<dim3(16, 64), 256, 0, stream>>>(hb, ffout, ao, BT, 1024, FFNH);
  // ca2 = ca_channel(x1) -> yb (free after w_o gemm)
  cain_k<<<BT, 256, 0, stream>>>(x1b, capi, cah);
  caconv_k<<<BT*CAD/256, 256, 0, stream>>>(cah, cacw, cag);
  caout_k<<<BT, 256, 0, stream>>>(cag, capo, yb);
  // vit gate
  vit_k<<<BT, 256, 0, stream>>>(x1b, vw1, vw2, vtb);
  vitsm_k<<<BT/256, 256, 0, stream>>>(vtb, vsm);
  // out = x1 + mlp*sig(gate)*(1+0.1*tanh(ca2))*vit
  final_k<<<BT*CC/256, 256, 0, stream>>>(x1b, ao, qb, yb, vsm, (float*)d_out);
}

// Round 3
// 2861.837 us; speedup vs baseline: 1.7765x; 1.7765x over previous
//
#include <hip/hip_runtime.h>

// ---- constants ----
#define BB 4
#define TT 1024
#define CC 1024
#define NH 16
#define NKV 4
#define HD 64
#define FFNH 4096
#define CAD 32
#define TQ 64
#define TK 64

__device__ __forceinline__ float sigf(float x){ return 1.f/(1.f+__expf(-x)); }
__device__ __forceinline__ float geluf(float x){ return 0.5f*x*(1.f+erff(x*0.70710678118654752f)); }

// ---- rmsnorm over last dim (1024) ----
__global__ __launch_bounds__(256) void rmsnorm_k(const float* __restrict__ x, float* __restrict__ o){
  int row = blockIdx.x;
  const float* xr = x + (size_t)row * CC;
  float v[4]; float ss = 0.f;
  #pragma unroll
  for (int i = 0; i < 4; i++){ v[i] = xr[threadIdx.x + 256*i]; ss += v[i]*v[i]; }
  #pragma unroll
  for (int off = 1; off < 64; off <<= 1) ss += __shfl_xor(ss, off);
  __shared__ float red[4];
  if ((threadIdx.x & 63) == 0) red[threadIdx.x >> 6] = ss;
  __syncthreads();
  float tot = red[0]+red[1]+red[2]+red[3];
  float rs = rsqrtf(tot * (1.f/CC) + 1e-6f);
  float* orow = o + (size_t)row * CC;
  #pragma unroll
  for (int i = 0; i < 4; i++) orow[threadIdx.x + 256*i] = v[i]*rs;
}

// ---- generic GEMM: C[M,N] = A[M,K] * W[N,K]^T (all fp32), EPI 0=none 1=relu^2 ----
template<int EPI>
__global__ __launch_bounds__(256) void gemm_k(
    const float* __restrict__ A, const float* __restrict__ W,
    float* __restrict__ C, int M, int N, int K)
{
  __shared__ float As[16][68];
  __shared__ float Ws[16][68];
  int tid = threadIdx.x;
  int m0 = blockIdx.y << 6;
  int n0 = blockIdx.x << 6;
  int lm = tid >> 2;
  int lk = (tid & 3) << 2;
  int tx = tid & 15;
  int ty = tid >> 4;
  float acc[4][4] = {};
  const float* Ap = A + (size_t)(m0 + lm)*K + lk;
  const float* Wp = W + (size_t)(n0 + lm)*K + lk;
  for (int k0 = 0; k0 < K; k0 += 16){
    float4 a4 = *(const float4*)(Ap + k0);
    float4 w4 = *(const float4*)(Wp + k0);
    As[lk+0][lm]=a4.x; As[lk+1][lm]=a4.y; As[lk+2][lm]=a4.z; As[lk+3][lm]=a4.w;
    Ws[lk+0][lm]=w4.x; Ws[lk+1][lm]=w4.y; Ws[lk+2][lm]=w4.z; Ws[lk+3][lm]=w4.w;
    __syncthreads();
    #pragma unroll
    for (int kk = 0; kk < 16; kk++){
      float a[4], bb[4];
      #pragma unroll
      for (int i=0;i<4;i++) a[i] = As[kk][ty*4+i];
      #pragma unroll
      for (int j=0;j<4;j++) bb[j] = Ws[kk][tx*4+j];
      #pragma unroll
      for (int i=0;i<4;i++)
        #pragma unroll
        for (int j=0;j<4;j++) acc[i][j] += a[i]*bb[j];
    }
    __syncthreads();
  }
  #pragma unroll
  for (int i=0;i<4;i++){
    float* cp = C + (size_t)(m0 + ty*4 + i)*N + n0 + tx*4;
    float4 o;
    float z;
    z = acc[i][0]; if (EPI==1){ z = fmaxf(z,0.f); z = z*z; } o.x = z;
    z = acc[i][1]; if (EPI==1){ z = fmaxf(z,0.f); z = z*z; } o.y = z;
    z = acc[i][2]; if (EPI==1){ z = fmaxf(z,0.f); z = z*z; } o.z = z;
    z = acc[i][3]; if (EPI==1){ z = fmaxf(z,0.f); z = z*z; } o.w = z;
    *(float4*)cp = o;
  }
}

// ---- rope + head-rmsnorm * 1.2 (one wave per (b,t,head)) ----
__global__ __launch_bounds__(64) void rope_rms_k(float* __restrict__ q,
    const float* __restrict__ cs, const float* __restrict__ sn, int nh){
  int idx = blockIdx.x;                 // (b*T + t)*nh + h
  int t = (idx / nh) & (TT-1);
  float* qp = q + (size_t)idx * HD;
  int d = threadIdx.x;
  int dl = d & 31;
  float c = cs[t*32 + dl], s = sn[t*32 + dl];
  float v0 = qp[d];
  float vp = qp[(d < 32) ? d + 32 : d - 32];
  float r = (d < 32) ? (v0*c + vp*s) : (v0*c - vp*s);
  float ss = r*r;
  #pragma unroll
  for (int off = 1; off < 64; off <<= 1) ss += __shfl_xor(ss, off);
  float rs = rsqrtf(ss*(1.f/HD) + 1e-6f) * 1.2f;
  qp[d] = r*rs;
}

// ---- v += 3*sigmoid(xn[:,:12] @ wg^T) * ve ----
__global__ __launch_bounds__(256) void gatev_k(float* __restrict__ v,
    const float* __restrict__ xn, const float* __restrict__ ve,
    const float* __restrict__ wg){
  int bt = blockIdx.x;
  int tid = threadIdx.x;
  int kv = tid >> 6;
  float s = 0.f;
  #pragma unroll
  for (int j = 0; j < 12; j++) s += xn[(size_t)bt*CC + j]*wg[kv*12+j];
  float gate = 3.f * sigf(s);
  size_t i = (size_t)bt*(NKV*HD) + tid;
  v[i] += gate * ve[i];
}

// ---- flash attention: block = (b,h,64-row q-tile); fused refine conv ----
__global__ __launch_bounds__(256) void fattn_k(
    const float* __restrict__ q, const float* __restrict__ k, const float* __restrict__ v,
    const float* __restrict__ pa, const float* __restrict__ rw,
    const float* __restrict__ alphap, float* __restrict__ y)
{
  int qt = blockIdx.x;         // 0..15
  int h  = blockIdx.y;
  int b  = blockIdx.z;
  int kv = h >> 2;
  int t0 = qt * TQ;
  int tid = threadIdx.x;
  int tx = tid & 15, ty = tid >> 4;

  __shared__ float Qs[HD][TQ+4];    // [d][row]  transposed
  __shared__ float Ks[HD][TK+4];    // [d][col]  transposed
  __shared__ float Vs[TK][HD+4];    // [kk][col]
  __shared__ float SB[66*68];       // pa tile [66][68]; later P^T [TK][TQ+4]

  // load Q tile transposed (once)
  for (int e = tid; e < TQ*HD/4; e += 256){
    int r = e >> 4;
    int d4 = (e & 15) << 2;
    const float* qp = q + (((size_t)(b*TT + t0 + r))*NH + h)*HD + d4;
    float4 val = *(const float4*)qp;
    Qs[d4+0][r] = val.x; Qs[d4+1][r] = val.y; Qs[d4+2][r] = val.z; Qs[d4+3][r] = val.w;
  }

  float alpha = *alphap;
  float w9[9];
  #pragma unroll
  for (int j = 0; j < 9; j++) w9[j] = rw[h*9+j]*alpha;

  float m_i[4], l_i[4], O[4][4];
  #pragma unroll
  for (int i=0;i<4;i++){ m_i[i] = -1e30f; l_i[i]=0.f;
    #pragma unroll
    for (int j=0;j<4;j++) O[i][j]=0.f; }

  for (int kt = 0; kt <= qt; kt++){
    int k0 = kt*TK;
    __syncthreads();   // prev PV / initial Q load complete
    // K tile transposed, V tile natural
    for (int e = tid; e < TK*HD/4; e += 256){
      int r = e >> 4;
      int d4 = (e & 15) << 2;
      const float* kp = k + (((size_t)(b*TT + k0 + r))*NKV + kv)*HD + d4;
      float4 val = *(const float4*)kp;
      Ks[d4+0][r]=val.x; Ks[d4+1][r]=val.y; Ks[d4+2][r]=val.z; Ks[d4+3][r]=val.w;
      const float* vp = v + (((size_t)(b*TT + k0 + r))*NKV + kv)*HD + d4;
      *(float4*)&Vs[r][d4] = *(const float4*)vp;
    }
    // pa tile with halo: rows t0-1..t0+64, cols k0-1..k0+64
    for (int e = tid; e < 66*66; e += 256){
      int li = e / 66, lj = e - li*66;
      int gr = t0 - 1 + li, gc = k0 - 1 + lj;
      float pv = 0.f;
      if (gr >= 0 && gr < TT && gc >= 0 && gc < TT)
        pv = pa[((size_t)(b*NH + h)*TT + gr)*TT + gc];
      SB[li*68 + lj] = pv;
    }
    __syncthreads();
    // S = Q K^T
    float s[4][4];
    #pragma unroll
    for (int i=0;i<4;i++)
      #pragma unroll
      for (int j=0;j<4;j++) s[i][j]=0.f;
    #pragma unroll 8
    for (int d = 0; d < HD; d++){
      float4 a4 = *(const float4*)&Qs[d][ty*4];
      float4 b4 = *(const float4*)&Ks[d][tx*4];
      float av[4] = {a4.x,a4.y,a4.z,a4.w};
      float bv[4] = {b4.x,b4.y,b4.z,b4.w};
      #pragma unroll
      for (int i=0;i<4;i++)
        #pragma unroll
        for (int j=0;j<4;j++) s[i][j] += av[i]*bv[j];
    }
    // conv + mask + scale
    #pragma unroll
    for (int i=0;i<4;i++){
      int lr = ty*4 + i;
      #pragma unroll
      for (int j=0;j<4;j++){
        int lc = tx*4 + j;
        float cv = 0.f;
        #pragma unroll
        for (int dy=0; dy<3; dy++)
          #pragma unroll
          for (int dx=0; dx<3; dx++)
            cv += SB[(lr+dy)*68 + (lc+dx)] * w9[dy*3+dx];
        float sv = s[i][j]*0.125f + cv;
        if (k0 + lc > t0 + lr) sv = -1e30f;   // causal
        s[i][j] = sv;
      }
    }
    // online softmax (row groups = 16 lanes sharing ty)
    float p[4][4];
    #pragma unroll
    for (int i=0;i<4;i++){
      float rm = fmaxf(fmaxf(s[i][0],s[i][1]),fmaxf(s[i][2],s[i][3]));
      #pragma unroll
      for (int off=1; off<16; off<<=1) rm = fmaxf(rm, __shfl_xor(rm, off));
      float mn = fmaxf(m_i[i], rm);
      float sc = __expf(m_i[i] - mn);
      m_i[i] = mn;
      float rs = 0.f;
      #pragma unroll
      for (int j=0;j<4;j++){ float pv = __expf(s[i][j]-mn); p[i][j]=pv; rs += pv; }
      #pragma unroll
      for (int off=1; off<16; off<<=1) rs += __shfl_xor(rs, off);
      l_i[i] = l_i[i]*sc + rs;
      #pragma unroll
      for (int j=0;j<4;j++) O[i][j] *= sc;
    }
    __syncthreads();   // conv reads of SB done
    // P^T into SB: Ps[kk][row], stride 68
    #pragma unroll
    for (int j=0;j<4;j++)
      #pragma unroll
      for (int i=0;i<4;i++)
        SB[(tx*4+j)*68 + ty*4 + i] = p[i][j];
    __syncthreads();
    // O += P V
    #pragma unroll 8
    for (int kk=0; kk<TK; kk++){
      float4 a4 = *(const float4*)&SB[kk*68 + ty*4];
      float4 b4 = *(const float4*)&Vs[kk][tx*4];
      float av[4]={a4.x,a4.y,a4.z,a4.w};
      float bv[4]={b4.x,b4.y,b4.z,b4.w};
      #pragma unroll
      for (int i=0;i<4;i++)
        #pragma unroll
        for (int j=0;j<4;j++) O[i][j] += av[i]*bv[j];
    }
  }
  // write y[b][t][h][d]
  #pragma unroll
  for (int i=0;i<4;i++){
    float inv = 1.f / l_i[i];
    int t = t0 + ty*4 + i;
    float* yp = y + (((size_t)(b*TT + t))*NH + h)*HD + tx*4;
    float4 o4 = { O[i][0]*inv, O[i][1]*inv, O[i][2]*inv, O[i][3]*inv };
    *(float4*)yp = o4;
  }
}

// ---- CA: in-projection (K=1024 -> 32) ----
__global__ __launch_bounds__(256) void cain_k(const float* __restrict__ x,
    const float* __restrict__ pi, float* __restrict__ out){
  int bt = blockIdx.x;
  __shared__ float xs[CC];
  __shared__ float pr[8][33];
  for (int i = threadIdx.x; i < CC; i += 256) xs[i] = x[(size_t)bt*CC + i];
  __syncthreads();
  int d = threadIdx.x & 31, sl = threadIdx.x >> 5;
  const float* pip = pi + (size_t)d*CC + sl*128;
  float s = 0.f;
  #pragma unroll 8
  for (int i = 0; i < 128; i++) s += xs[sl*128+i]*pip[i];
  pr[sl][d] = s;
  __syncthreads();
  if (threadIdx.x < 32){
    float tot = 0.f;
    #pragma unroll
    for (int j = 0; j < 8; j++) tot += pr[j][threadIdx.x];
    out[(size_t)bt*CAD + threadIdx.x] = tot;
  }
}

// ---- CA: depthwise conv over T + exact gelu ----
__global__ __launch_bounds__(256) void caconv_k(const float* __restrict__ hin,
    const float* __restrict__ cw, float* __restrict__ gout){
  int i = blockIdx.x*256 + threadIdx.x;   // < B*T*32
  int d = i & 31;
  int bt = i >> 5;
  int t = bt & (TT-1);
  float cc = hin[i];
  float hm = (t > 0)      ? hin[i-32] : 0.f;
  float hp = (t < TT-1)   ? hin[i+32] : 0.f;
  float hc = cc + 0.1f*(hm*cw[d*3] + cc*cw[d*3+1] + hp*cw[d*3+2]);
  gout[i] = geluf(hc);
}

// ---- CA: out-projection (K=32 -> 1024) ----
__global__ __launch_bounds__(256) void caout_k(const float* __restrict__ g,
    const float* __restrict__ po, float* __restrict__ out){
  int bt = blockIdx.x;
  __shared__ float gs[CAD];
  if (threadIdx.x < CAD) gs[threadIdx.x] = g[(size_t)bt*CAD + threadIdx.x];
  __syncthreads();
  for (int c = threadIdx.x; c < CC; c += 256){
    const float* pp = po + (size_t)c*CAD;
    float s = 0.f;
    #pragma unroll
    for (int d2 = 0; d2 < CAD; d2++) s += gs[d2]*pp[d2];
    out[(size_t)bt*CC + c] = s;
  }
}

// ---- x1 = x + attn_out * (1 + 0.1*tanh(ca1)) ----
__global__ __launch_bounds__(256) void x1_k(const float* __restrict__ x,
    const float* __restrict__ ao, const float* __restrict__ ca1, float* __restrict__ x1){
  size_t i = (size_t)blockIdx.x*256 + threadIdx.x;
  x1[i] = x[i] + ao[i] * (1.f + 0.1f*tanhf(ca1[i]));
}

// ---- FFN depthwise conv over T (one of 4 iterations) ----
__global__ __launch_bounds__(256) void ffnconv_k(const float* __restrict__ hin,
    const float* __restrict__ cw, float* __restrict__ hout){
  size_t i = (size_t)blockIdx.x*256 + threadIdx.x;   // < B*T*4096
  int c = (int)(i & (FFNH-1));
  size_t bt = i >> 12;
  int t = (int)(bt & (TT-1));
  float cc = hin[i];
  float hm = (t > 0)    ? hin[i - FFNH] : 0.f;
  float hp = (t < TT-1) ? hin[i + FFNH] : 0.f;
  hout[i] = cc + 0.1f*(hm*cw[c*3] + cc*cw[c*3+1] + hp*cw[c*3+2]);
}

// ---- vit scalar gate ----
__global__ __launch_bounds__(256) void vit_k(const float* __restrict__ x1,
    const float* __restrict__ w1, const float* __restrict__ w2,
    float* __restrict__ vout){
  int bt = blockIdx.x;
  __shared__ float xs[CC];
  __shared__ float pr[8][33];
  __shared__ float g32[32];
  for (int i = threadIdx.x; i < CC; i += 256) xs[i] = x1[(size_t)bt*CC + i];
  __syncthreads();
  int d = threadIdx.x & 31, sl = threadIdx.x >> 5;
  const float* wp = w1 + (size_t)d*CC + sl*128;
  float s = 0.f;
  #pragma unroll 8
  for (int i = 0; i < 128; i++) s += xs[sl*128+i]*wp[i];
  pr[sl][d] = s;
  __syncthreads();
  if (threadIdx.x < 32){
    float tot = 0.f;
    #pragma unroll
    for (int j = 0; j < 8; j++) tot += pr[j][threadIdx.x];
    g32[threadIdx.x] = geluf(tot);
  }
  __syncthreads();
  if (threadIdx.x == 0){
    float s2 = 0.f;
    #pragma unroll
    for (int d2 = 0; d2 < 32; d2++) s2 += g32[d2]*w2[d2];
    vout[bt] = sigf(s2);
  }
}

// ---- vit smoothing + threshold ----
__global__ __launch_bounds__(256) void vitsm_k(const float* __restrict__ vin, float* __restrict__ vout){
  int i = blockIdx.x*256 + threadIdx.x;  // < B*T
  int t = i & (TT-1), b = i >> 10;
  float s = 0.f;
  #pragma unroll
  for (int dd = -2; dd <= 2; dd++){
    int tt = t + dd;
    if (tt >= 0 && tt < TT) s += vin[(b << 10) + tt];
  }
  s *= 0.2f;
  float vv = 0.7f*vin[i] + 0.3f*s;
  vout[i] = (vv > 0.3f) ? vv : 0.1f*vv;
}

// ---- final: out = x1 + mlp*sig(g)*(1+0.1*tanh(ca2)) * vit ----
__global__ __launch_bounds__(256) void final_k(const float* __restrict__ x1,
    const float* __restrict__ mlpraw, const float* __restrict__ g,
    const float* __restrict__ ca2, const float* __restrict__ vsm,
    float* __restrict__ out){
  size_t i = (size_t)blockIdx.x*256 + threadIdx.x;
  size_t bt = i >> 10;
  float mlp = mlpraw[i] * sigf(g[i]) * (1.f + 0.1f*tanhf(ca2[i]));
  out[i] = x1[i] + mlp * vsm[bt];
}

extern "C" void kernel_launch(void* const* d_in, const int* in_sizes, int n_in,
                              void* d_out, int out_size, void* d_ws, size_t ws_size,
                              hipStream_t stream) {
  (void)in_sizes; (void)n_in; (void)out_size; (void)ws_size;
  const float* x     = (const float*)d_in[0];
  const float* ve    = (const float*)d_in[1];
  const float* cs    = (const float*)d_in[2];
  const float* sn    = (const float*)d_in[3];
  const float* pa    = (const float*)d_in[4];
  const float* w_q   = (const float*)d_in[5];
  const float* w_k   = (const float*)d_in[6];
  const float* w_v   = (const float*)d_in[7];
  const float* w_o   = (const float*)d_in[8];
  const float* w_vg  = (const float*)d_in[9];
  const float* rfw   = (const float*)d_in[10];
  const float* ralp  = (const float*)d_in[11];
  const float* capi  = (const float*)d_in[12];
  const float* cacw  = (const float*)d_in[13];
  const float* capo  = (const float*)d_in[14];
  const float* ffin  = (const float*)d_in[15];
  const float* ffcw  = (const float*)d_in[16];
  const float* ffout = (const float*)d_in[17];
  const float* ffgt  = (const float*)d_in[18];
  const float* vw1   = (const float*)d_in[19];
  const float* vw2   = (const float*)d_in[20];

  float* ws = (float*)d_ws;
  const size_t M4 = (size_t)BB*TT*CC;       // 4,194,304
  float* xn  = ws;                          // M4   (reused: ca1)
  float* qb  = ws + M4;                     // M4   (reused: ffn gate)
  float* kb  = ws + 2*M4;                   // M4/4
  float* vb  = ws + 2*M4 + M4/4;            // M4/4
  float* yb  = ws + 2*M4 + M4/2;            // M4   (reused: ca2)
  float* ao  = ws + 3*M4 + M4/2;            // M4   (reused: mlp raw)
  float* x1b = ws + 4*M4 + M4/2;            // M4
  float* xm  = ws + 5*M4 + M4/2;            // M4
  float* hb  = ws + 6*M4 + M4/2;            // 4*M4
  float* h2  = ws + 10*M4 + M4/2;           // 4*M4
  float* cah = ws + 14*M4 + M4/2;           // 128K
  float* cag = cah + (size_t)BB*TT*CAD;     // 128K
  float* vtb = cag + (size_t)BB*TT*CAD;     // 4K
  float* vsm = vtb + (size_t)BB*TT;         // 4K

  const int BT = BB*TT;                     // 4096

  rmsnorm_k<<<BT, 256, 0, stream>>>(x, xn);
  gemm_k<0><<<dim3(16, 64), 256, 0, stream>>>(xn, w_q, qb, BT, 1024, 1024);
  gemm_k<0><<<dim3(4, 64), 256, 0, stream>>>(xn, w_k, kb, BT, 256, 1024);
  gemm_k<0><<<dim3(4, 64), 256, 0, stream>>>(xn, w_v, vb, BT, 256, 1024);
  rope_rms_k<<<BT*NH, 64, 0, stream>>>(qb, cs, sn, NH);
  rope_rms_k<<<BT*NKV, 64, 0, stream>>>(kb, cs, sn, NKV);
  gatev_k<<<BT, 256, 0, stream>>>(vb, xn, ve, w_vg);
  // flash attention with fused refine conv
  fattn_k<<<dim3(TT/TQ, NH, BB), 256, 0, stream>>>(qb, kb, vb, pa, rfw, ralp, yb);
  gemm_k<0><<<dim3(16, 64), 256, 0, stream>>>(yb, w_o, ao, BT, 1024, 1024);
  cain_k<<<BT, 256, 0, stream>>>(x, capi, cah);
  caconv_k<<<BT*CAD/256, 256, 0, stream>>>(cah, cacw, cag);
  caout_k<<<BT, 256, 0, stream>>>(cag, capo, xn);
  x1_k<<<BT*CC/256, 256, 0, stream>>>(x, ao, xn, x1b);
  rmsnorm_k<<<BT, 256, 0, stream>>>(x1b, xm);
  gemm_k<1><<<dim3(64, 64), 256, 0, stream>>>(xm, ffin, hb, BT, FFNH, 1024);
  ffnconv_k<<<BT*FFNH/256, 256, 0, stream>>>(hb, ffcw, h2);
  ffnconv_k<<<BT*FFNH/256, 256, 0, stream>>>(h2, ffcw, hb);
  ffnconv_k<<<BT*FFNH/256, 256, 0, stream>>>(hb, ffcw, h2);
  ffnconv_k<<<BT*FFNH/256, 256, 0, stream>>>(h2, ffcw, hb);
  gemm_k<0><<<dim3(16, 64), 256, 0, stream>>>(xm, ffgt, qb, BT, 1024, 1024);
  gemm_k<0><<<dim3(16, 64), 256, 0, stream>>>(hb, ffout, ao, BT, 1024, FFNH);
  cain_k<<<BT, 256, 0, stream>>>(x1b, capi, cah);
  caconv_k<<<BT*CAD/256, 256, 0, stream>>>(cah, cacw, cag);
  caout_k<<<BT, 256, 0, stream>>>(cag, capo, yb);
  vit_k<<<BT, 256, 0, stream>>>(x1b, vw1, vw2, vtb);
  vitsm_k<<<BT/256, 256, 0, stream>>>(vtb, vsm);
  final_k<<<BT*CC/256, 256, 0, stream>>>(x1b, ao, qb, yb, vsm, (float*)d_out);
}